// Round 1
// baseline (392.918 us; speedup 1.0000x reference)
//
#include <hip/hip_runtime.h>

typedef __attribute__((ext_vector_type(8))) short short8;
typedef __attribute__((ext_vector_type(4))) float f32x4;
typedef __attribute__((ext_vector_type(4))) unsigned short u16x4;
typedef __attribute__((ext_vector_type(4))) unsigned int u32x4;

#define DEV static __device__ __forceinline__

constexpr int NN = 50000;       // nodes
constexpr int NE = 800000;      // edges
constexpr int NT_N = NN / 16;   // 3125 node tiles of 16 rows
constexpr int NT_E = NE / 16;   // 50000 edge tiles of 16 rows
constexpr float EPS_BN = 1e-5f;
constexpr float EPS_NORM = 1e-12f;

// f32 -> bf16 (round-to-nearest-even)
DEV unsigned short f2b(float f) {
  unsigned u = __float_as_uint(f);
  return (unsigned short)((u + 0x7FFFu + ((u >> 16) & 1u)) >> 16);
}
DEV float b2f(unsigned short s) { return __uint_as_float(((unsigned)s) << 16); }

// A-fragment for mfma_f32_16x16x32_bf16 from a row-major [*][64] f32 matrix.
// lane holds row = row0 + (lane&15), k = kbase + (lane>>4)*8 + j  (j=0..7)
DEV short8 load_a_frag(const float* __restrict__ base, int row, int kbase) {
  const f32x4* p = reinterpret_cast<const f32x4*>(base + row * 64 + kbase);
  f32x4 v0 = p[0], v1 = p[1];
  short8 a;
  a[0] = f2b(v0[0]); a[1] = f2b(v0[1]); a[2] = f2b(v0[2]); a[3] = f2b(v0[3]);
  a[4] = f2b(v1[0]); a[5] = f2b(v1[1]); a[6] = f2b(v1[2]); a[7] = f2b(v1[3]);
  return a;
}

// B-fragment: W is [K][64] row-major f32. lane holds col = c0 + (lane&15),
// k = kbase + (lane>>4)*8 + j.
DEV short8 load_w_frag(const float* __restrict__ W, int kbase, int c0, int lane) {
  int kr = kbase + ((lane >> 4) << 3);
  int cc = c0 + (lane & 15);
  short8 b;
#pragma unroll
  for (int j = 0; j < 8; ++j) b[j] = f2b(W[(kr + j) * 64 + cc]);
  return b;
}

DEV f32x4 mfma16(short8 a, short8 b, f32x4 c) {
  return __builtin_amdgcn_mfma_f32_16x16x32_bf16(a, b, c, 0, 0, 0);
}

// ---------------- init: zero c (as +0.0f bits) and stats accumulators --------
__global__ void k_init(u32x4* __restrict__ cbuf4, float* __restrict__ stats) {
  int i = blockIdx.x * 256 + threadIdx.x;
  if (i < NN * 16) {  // NN*64/4 vec4 elements
    u32x4 z = {0u, 0u, 0u, 0u};
    cbuf4[i] = z;
  }
  if (i < 256) stats[i] = 0.0f;
}

// ---------------- K1: Ah = h@A_W + A_b ; Bh = h@B_W + B_b --------------------
__global__ void __launch_bounds__(256) k_node_lin(
    const float* __restrict__ h, const float* __restrict__ AW,
    const float* __restrict__ Ab, const float* __restrict__ BW,
    const float* __restrict__ Bb, float* __restrict__ Ah,
    float* __restrict__ Bh) {
  int lane = threadIdx.x & 63, warp = threadIdx.x >> 6;
  int tile = blockIdx.x * 4 + warp;
  if (tile >= NT_N) return;

  short8 wa[4][2], wb[4][2];
  float ab[4], bb[4];
#pragma unroll
  for (int t = 0; t < 4; ++t) {
#pragma unroll
    for (int kk = 0; kk < 2; ++kk) {
      wa[t][kk] = load_w_frag(AW, kk * 32, t * 16, lane);
      wb[t][kk] = load_w_frag(BW, kk * 32, t * 16, lane);
    }
    ab[t] = Ab[t * 16 + (lane & 15)];
    bb[t] = Bb[t * 16 + (lane & 15)];
  }

  int row0 = tile * 16;
  int ar = row0 + (lane & 15), kb = (lane >> 4) * 8;
  short8 a0 = load_a_frag(h, ar, kb);
  short8 a1 = load_a_frag(h, ar, 32 + kb);

  f32x4 zero = {0.f, 0.f, 0.f, 0.f};
  f32x4 accA[4], accB[4];
#pragma unroll
  for (int t = 0; t < 4; ++t) {
    accA[t] = mfma16(a0, wa[t][0], zero);
    accA[t] = mfma16(a1, wa[t][1], accA[t]);
    accB[t] = mfma16(a0, wb[t][0], zero);
    accB[t] = mfma16(a1, wb[t][1], accB[t]);
  }
#pragma unroll
  for (int t = 0; t < 4; ++t)
#pragma unroll
    for (int q = 0; q < 4; ++q) {
      int row = row0 + (lane >> 4) * 4 + q;
      int col = t * 16 + (lane & 15);
      Ah[row * 64 + col] = accA[t][q] + ab[t];
      Bh[row * 64 + col] = accB[t][q] + bb[t];
    }
}

// ---------------- K2: edge pass -------------------------------------------
// e_ij = e@C_W + C_b + Bh[src] + Bh[dst]; msg = relu(sigmoid(e_ij)*Ah[src])
// atomicMax into c[dst]; stage relu(e_ij); accumulate column sum/sumsq.
__global__ void __launch_bounds__(256) k_edge(
    const float* __restrict__ e, const int* __restrict__ src,
    const int* __restrict__ dst, const float* __restrict__ CW,
    const float* __restrict__ Cb, const float* __restrict__ Ah,
    const float* __restrict__ Bh, unsigned* __restrict__ cbuf,
    float* __restrict__ gsum, float* __restrict__ gsq,
    float* __restrict__ stage_f32, unsigned short* __restrict__ stage_b16,
    int use_b16) {
  __shared__ float ssum[64], ssq[64];
  int lane = threadIdx.x & 63, warp = threadIdx.x >> 6;

  short8 cw[4][2];
  float cb[4];
#pragma unroll
  for (int t = 0; t < 4; ++t) {
#pragma unroll
    for (int kk = 0; kk < 2; ++kk) cw[t][kk] = load_w_frag(CW, kk * 32, t * 16, lane);
    cb[t] = Cb[t * 16 + (lane & 15)];
  }

  float es[4] = {0.f, 0.f, 0.f, 0.f}, eq[4] = {0.f, 0.f, 0.f, 0.f};
  f32x4 zero = {0.f, 0.f, 0.f, 0.f};
  int stride = gridDim.x * 4;

  for (int tile = blockIdx.x * 4 + warp; tile < NT_E; tile += stride) {
    int e0 = tile * 16;
    int ar = e0 + (lane & 15), kb = (lane >> 4) * 8;
    short8 a0 = load_a_frag(e, ar, kb);
    short8 a1 = load_a_frag(e, ar, 32 + kb);

    f32x4 acc[4];
#pragma unroll
    for (int t = 0; t < 4; ++t) {
      acc[t] = mfma16(a0, cw[t][0], zero);
      acc[t] = mfma16(a1, cw[t][1], acc[t]);
    }

#pragma unroll
    for (int q = 0; q < 4; ++q) {
      int er = e0 + (lane >> 4) * 4 + q;
      int s = src[er], d = dst[er];
#pragma unroll
      for (int t = 0; t < 4; ++t) {
        int col = t * 16 + (lane & 15);
        float eij = acc[t][q] + cb[t] + Bh[s * 64 + col] + Bh[d * 64 + col];
        float sg = __fdividef(1.0f, 1.0f + __expf(-eij));
        float m = sg * Ah[s * 64 + col];
        m = (m > 0.0f) ? m : 0.0f;  // canonical +0, never -0
        atomicMax(&cbuf[d * 64 + col], __float_as_uint(m));
        float re = (eij > 0.0f) ? eij : 0.0f;
        if (use_b16) stage_b16[er * 64 + col] = f2b(re);
        else         stage_f32[er * 64 + col] = re;
        es[t] += re;
        eq[t] += re * re;
      }
    }
  }

  if (threadIdx.x < 64) { ssum[threadIdx.x] = 0.f; ssq[threadIdx.x] = 0.f; }
  __syncthreads();
#pragma unroll
  for (int t = 0; t < 4; ++t) {
    int col = t * 16 + (lane & 15);
    atomicAdd(&ssum[col], es[t]);
    atomicAdd(&ssq[col], eq[t]);
  }
  __syncthreads();
  if (threadIdx.x < 64) {
    atomicAdd(&gsum[threadIdx.x], ssum[threadIdx.x]);
    atomicAdd(&gsq[threadIdx.x], ssq[threadIdx.x]);
  }
}

// ---------------- K3: bundle = [h,c]@W_apply + b; L2-norm rows; relu ---------
__global__ void __launch_bounds__(256) k_apply(
    const float* __restrict__ h, const float* __restrict__ cbuf_f,
    const float* __restrict__ Wap, const float* __restrict__ bap,
    float* __restrict__ stage_h, float* __restrict__ gsum,
    float* __restrict__ gsq) {
  __shared__ float ssum[64], ssq[64];
  int lane = threadIdx.x & 63, warp = threadIdx.x >> 6;
  int tile = blockIdx.x * 4 + warp;

  float hs[4] = {0.f, 0.f, 0.f, 0.f}, hq[4] = {0.f, 0.f, 0.f, 0.f};

  if (tile < NT_N) {
    short8 w[4][4];
    float ba[4];
#pragma unroll
    for (int t = 0; t < 4; ++t) {
#pragma unroll
      for (int kk = 0; kk < 4; ++kk) w[t][kk] = load_w_frag(Wap, kk * 32, t * 16, lane);
      ba[t] = bap[t * 16 + (lane & 15)];
    }

    int row0 = tile * 16;
    int ar = row0 + (lane & 15), kb = (lane >> 4) * 8;
    short8 a0 = load_a_frag(h, ar, kb);
    short8 a1 = load_a_frag(h, ar, 32 + kb);
    short8 a2 = load_a_frag(cbuf_f, ar, kb);
    short8 a3 = load_a_frag(cbuf_f, ar, 32 + kb);

    f32x4 zero = {0.f, 0.f, 0.f, 0.f};
    f32x4 acc[4];
#pragma unroll
    for (int t = 0; t < 4; ++t) {
      acc[t] = mfma16(a0, w[t][0], zero);
      acc[t] = mfma16(a1, w[t][1], acc[t]);
      acc[t] = mfma16(a2, w[t][2], acc[t]);
      acc[t] = mfma16(a3, w[t][3], acc[t]);
    }

    float v[4][4];
#pragma unroll
    for (int t = 0; t < 4; ++t)
#pragma unroll
      for (int q = 0; q < 4; ++q) v[t][q] = acc[t][q] + ba[t];

#pragma unroll
    for (int q = 0; q < 4; ++q) {
      float sq = v[0][q] * v[0][q] + v[1][q] * v[1][q] + v[2][q] * v[2][q] +
                 v[3][q] * v[3][q];
      sq += __shfl_xor(sq, 1);
      sq += __shfl_xor(sq, 2);
      sq += __shfl_xor(sq, 4);
      sq += __shfl_xor(sq, 8);
      float sc = __fdividef(1.0f, fmaxf(sqrtf(sq), EPS_NORM));
      int row = row0 + (lane >> 4) * 4 + q;
#pragma unroll
      for (int t = 0; t < 4; ++t) {
        float hn = v[t][q] * sc;
        hn = (hn > 0.0f) ? hn : 0.0f;
        stage_h[row * 64 + t * 16 + (lane & 15)] = hn;
        hs[t] += hn;
        hq[t] += hn * hn;
      }
    }
  }

  if (threadIdx.x < 64) { ssum[threadIdx.x] = 0.f; ssq[threadIdx.x] = 0.f; }
  __syncthreads();
#pragma unroll
  for (int t = 0; t < 4; ++t) {
    int col = t * 16 + (lane & 15);
    atomicAdd(&ssum[col], hs[t]);
    atomicAdd(&ssq[col], hq[t]);
  }
  __syncthreads();
  if (threadIdx.x < 64) {
    atomicAdd(&gsum[threadIdx.x], ssum[threadIdx.x]);
    atomicAdd(&gsq[threadIdx.x], ssq[threadIdx.x]);
  }
}

// ---------------- K4: fold stats into scale/offset per column ---------------
__global__ void k_stats(const float* __restrict__ sum_e, const float* __restrict__ sq_e,
                        const float* __restrict__ sum_h, const float* __restrict__ sq_h,
                        const float* __restrict__ gamma_e, const float* __restrict__ beta_e,
                        const float* __restrict__ gamma_h, const float* __restrict__ beta_h,
                        float* __restrict__ se, float* __restrict__ oe,
                        float* __restrict__ sh, float* __restrict__ oh) {
  int j = threadIdx.x;
  if (j < 64) {
    float mu = sum_e[j] / (float)NE;
    float var = fmaxf(sq_e[j] / (float)NE - mu * mu, 0.0f);
    float s = gamma_e[j] / sqrtf(var + EPS_BN);
    se[j] = s;
    oe[j] = beta_e[j] - mu * s;
    mu = sum_h[j] / (float)NN;
    var = fmaxf(sq_h[j] / (float)NN - mu * mu, 0.0f);
    s = gamma_h[j] / sqrtf(var + EPS_BN);
    sh[j] = s;
    oh[j] = beta_h[j] - mu * s;
  }
}

// ---------------- K5: h_out = h + BN(h_new)  (in place over stage) ----------
__global__ void __launch_bounds__(256) k_fin_h(const float* __restrict__ h,
                                               const float* __restrict__ sh,
                                               const float* __restrict__ oh,
                                               float* __restrict__ outh) {
  int i = (blockIdx.x * 256 + threadIdx.x) * 4;
  if (i >= NN * 64) return;
  f32x4 x = *reinterpret_cast<const f32x4*>(outh + i);
  f32x4 hv = *reinterpret_cast<const f32x4*>(h + i);
  int c0 = i & 63;
  f32x4 r;
#pragma unroll
  for (int j = 0; j < 4; ++j) r[j] = hv[j] + x[j] * sh[c0 + j] + oh[c0 + j];
  *reinterpret_cast<f32x4*>(outh + i) = r;
}

// ---------------- K6: e_out = e + BN(relu_e)  ------------------------------
__global__ void __launch_bounds__(256) k_fin_e(const float* __restrict__ e,
                                               const float* __restrict__ se,
                                               const float* __restrict__ oe,
                                               const unsigned short* __restrict__ stb,
                                               int use_b16,
                                               float* __restrict__ oute) {
  int i = (blockIdx.x * 256 + threadIdx.x) * 4;
  if (i >= NE * 64) return;
  f32x4 x;
  if (use_b16) {
    u16x4 u = *reinterpret_cast<const u16x4*>(stb + i);
    x[0] = b2f(u[0]); x[1] = b2f(u[1]); x[2] = b2f(u[2]); x[3] = b2f(u[3]);
  } else {
    x = *reinterpret_cast<const f32x4*>(oute + i);
  }
  f32x4 ev = *reinterpret_cast<const f32x4*>(e + i);
  int c0 = i & 63;
  f32x4 r;
#pragma unroll
  for (int j = 0; j < 4; ++j) r[j] = ev[j] + x[j] * se[c0 + j] + oe[c0 + j];
  *reinterpret_cast<f32x4*>(oute + i) = r;
}

// ---------------------------------------------------------------------------
extern "C" void kernel_launch(void* const* d_in, const int* in_sizes, int n_in,
                              void* d_out, int out_size, void* d_ws, size_t ws_size,
                              hipStream_t stream) {
  (void)in_sizes; (void)n_in; (void)out_size;
  const float* h   = (const float*)d_in[0];
  const float* e   = (const float*)d_in[1];
  const int*   src = (const int*)d_in[2];
  const int*   dst = (const int*)d_in[3];
  const float* AW  = (const float*)d_in[4];
  const float* Ab  = (const float*)d_in[5];
  const float* BW  = (const float*)d_in[6];
  const float* Bb  = (const float*)d_in[7];
  const float* CW  = (const float*)d_in[8];
  const float* Cb  = (const float*)d_in[9];
  const float* Wap = (const float*)d_in[10];
  const float* bap = (const float*)d_in[11];
  const float* gamma_h = (const float*)d_in[12];
  const float* beta_h  = (const float*)d_in[13];
  const float* gamma_e = (const float*)d_in[14];
  const float* beta_e  = (const float*)d_in[15];

  float* ws = (float*)d_ws;
  float* Ah = ws;                         // 3.2M floats
  float* Bh = ws + 3200000;               // 3.2M floats
  unsigned* cbuf = (unsigned*)(ws + 6400000);  // 3.2M u32
  float* stats = ws + 9600000;            // 512 floats
  float* sum_e = stats;
  float* sq_e  = stats + 64;
  float* sum_h = stats + 128;
  float* sq_h  = stats + 192;
  float* se    = stats + 256;
  float* oe    = stats + 320;
  float* sh    = stats + 384;
  float* oh    = stats + 448;

  size_t base_bytes = (size_t)(9600000 + 512) * 4;
  int use_b16 = (ws_size >= base_bytes + (size_t)NE * 64 * 2) ? 1 : 0;
  unsigned short* stage_b16 = (unsigned short*)(ws + 9600512);

  float* outh = (float*)d_out;
  float* oute = outh + (size_t)NN * 64;
  float* stage_f32 = oute;  // in-place staging in the e_out region

  k_init<<<3125, 256, 0, stream>>>((u32x4*)cbuf, stats);
  k_node_lin<<<(NT_N + 3) / 4, 256, 0, stream>>>(h, AW, Ab, BW, Bb, Ah, Bh);
  k_edge<<<2048, 256, 0, stream>>>(e, src, dst, CW, Cb, Ah, Bh, cbuf, sum_e,
                                   sq_e, stage_f32, stage_b16, use_b16);
  k_apply<<<(NT_N + 3) / 4, 256, 0, stream>>>(h, (const float*)cbuf, Wap, bap,
                                              outh, sum_h, sq_h);
  k_stats<<<1, 64, 0, stream>>>(sum_e, sq_e, sum_h, sq_h, gamma_e, beta_e,
                                gamma_h, beta_h, se, oe, sh, oh);
  k_fin_h<<<NN * 64 / 1024, 256, 0, stream>>>(h, sh, oh, outh);
  k_fin_e<<<NE * 64 / 1024, 256, 0, stream>>>(e, se, oe, stage_b16, use_b16, oute);
}